// Round 1
// baseline (1566.161 us; speedup 1.0000x reference)
//
#include <hip/hip_runtime.h>
#include <hip/hip_bf16.h>
#include <cmath>

// ---------------------------------------------------------------------------
// TextEncoder: 4-layer post-LN transformer, B=2 N=2048 D=1024 H=16 dh=64 FF=4096
// Strategy R0: bf16 MFMA GEMMs (fp32 accum), flash attention, fp32 LN/residual.
// ---------------------------------------------------------------------------

typedef __attribute__((ext_vector_type(8))) short bf16x8;
typedef __attribute__((ext_vector_type(4))) float f32x4;
typedef __hip_bfloat16 bf16;

#define DEV static __device__ __forceinline__

DEV unsigned short f2b(float f) {
    bf16 h = __float2bfloat16(f);
    return *reinterpret_cast<unsigned short*>(&h);
}

DEV float gelu_exact(float x) {
    return 0.5f * x * (1.0f + erff(x * 0.70710678118654752440f));
}

// ---- weight transpose + cast: Wt[l][n][k] = (bf16) W[l][k][n] --------------
__global__ __launch_bounds__(256) void transpose_cast(const float* __restrict__ W,
                                                      bf16* __restrict__ Wt,
                                                      int K, int Nm) {
    __shared__ float tile[32][33];
    const int l = blockIdx.z;
    const float* Wl = W + (size_t)l * K * Nm;
    bf16* Wtl = Wt + (size_t)l * K * Nm;
    const int n0 = blockIdx.x * 32, k0 = blockIdx.y * 32;
    const int tx = threadIdx.x, ty = threadIdx.y;
#pragma unroll
    for (int i = 0; i < 4; ++i)
        tile[ty + 8 * i][tx] = Wl[(size_t)(k0 + ty + 8 * i) * Nm + n0 + tx];
    __syncthreads();
#pragma unroll
    for (int i = 0; i < 4; ++i)
        Wtl[(size_t)(n0 + ty + 8 * i) * K + k0 + tx] = __float2bfloat16(tile[tx][ty + 8 * i]);
}

// ---- elementwise fp32 -> bf16 ----------------------------------------------
__global__ __launch_bounds__(256) void cast_bf16_k(const float* __restrict__ in,
                                                   bf16* __restrict__ out, int n4) {
    int i = blockIdx.x * 256 + threadIdx.x;
    if (i >= n4) return;
    float4 v = reinterpret_cast<const float4*>(in)[i];
    ushort4 o = { f2b(v.x), f2b(v.y), f2b(v.z), f2b(v.w) };
    reinterpret_cast<ushort4*>(out)[i] = o;
}

// ---- bf16 MFMA GEMM: C[M,Nm] = A[M,K] @ Bt[Nm,K]^T + bias ------------------
// EPI: 0 = bias -> bf16 out; 1 = bias+gelu -> bf16 out; 2 = bias+gelu -> f32 out
template <int EPI>
__global__ __launch_bounds__(256) void gemm_bf16(const bf16* __restrict__ A,
                                                 const bf16* __restrict__ Bt,
                                                 const float* __restrict__ bias,
                                                 void* __restrict__ Cout,
                                                 int M, int Nm, int K) {
    // 128x128 tile, BK=64, 4 waves in 2x2 grid, each wave 64x64 via 4x4 MFMA frags.
    __shared__ bf16 As[128][72];  // +8 pad -> row stride 144B, breaks bank conflicts
    __shared__ bf16 Bs[128][72];
    const int m0 = blockIdx.y * 128, n0 = blockIdx.x * 128;
    const int t = threadIdx.x;
    const int w = t >> 6, lane = t & 63;
    const int wr = (w >> 1) * 64, wc = (w & 1) * 64;
    const int lr = lane & 15, lg = lane >> 4;
    const int tr = t >> 3, tc = (t & 7) * 8;  // staging: 32 rows/pass, 8x16B per row

    f32x4 acc[4][4] = {};

    for (int k0 = 0; k0 < K; k0 += 64) {
        __syncthreads();  // protect previous iteration's LDS reads
#pragma unroll
        for (int p = 0; p < 4; ++p) {
            int row = p * 32 + tr;
            *reinterpret_cast<uint4*>(&As[row][tc]) =
                *reinterpret_cast<const uint4*>(A + (size_t)(m0 + row) * K + k0 + tc);
            *reinterpret_cast<uint4*>(&Bs[row][tc]) =
                *reinterpret_cast<const uint4*>(Bt + (size_t)(n0 + row) * K + k0 + tc);
        }
        __syncthreads();
#pragma unroll
        for (int kk = 0; kk < 2; ++kk) {
            const int lk = kk * 32 + lg * 8;
            bf16x8 a[4], b[4];
#pragma unroll
            for (int m = 0; m < 4; ++m)
                a[m] = *reinterpret_cast<const bf16x8*>(&As[wr + m * 16 + lr][lk]);
#pragma unroll
            for (int n = 0; n < 4; ++n)
                b[n] = *reinterpret_cast<const bf16x8*>(&Bs[wc + n * 16 + lr][lk]);
#pragma unroll
            for (int m = 0; m < 4; ++m)
#pragma unroll
                for (int n = 0; n < 4; ++n)
                    acc[m][n] = __builtin_amdgcn_mfma_f32_16x16x32_bf16(a[m], b[n], acc[m][n], 0, 0, 0);
        }
    }

    // epilogue: D layout col = lane&15, row = (lane>>4)*4 + j  [measured m89]
#pragma unroll
    for (int n = 0; n < 4; ++n) {
        const int col = n0 + wc + n * 16 + lr;
        const float bc = bias[col];
#pragma unroll
        for (int m = 0; m < 4; ++m) {
            const int row = m0 + wr + m * 16 + lg * 4;
#pragma unroll
            for (int j = 0; j < 4; ++j) {
                float v = acc[m][n][j] + bc;
                if (EPI >= 1) v = gelu_exact(v);
                if (EPI == 2)
                    reinterpret_cast<float*>(Cout)[(size_t)(row + j) * Nm + col] = v;
                else
                    reinterpret_cast<bf16*>(Cout)[(size_t)(row + j) * Nm + col] = __float2bfloat16(v);
            }
        }
    }
}

// ---- flash attention: qkv bf16 [B*N, 3*1024] -> o fp32 [B*N, 1024] ---------
// grid (N/64, B*H), block 256. Each wave owns 16 q-rows; KVBLK=64 staged in LDS.
__global__ __launch_bounds__(256) void attn_fwd(const bf16* __restrict__ qkv,
                                                float* __restrict__ o, int N) {
    __shared__ bf16 Ks[64][72];      // K tile [kv][dh], padded
    __shared__ bf16 Vt[64][72];      // V^T tile [dh][kv], padded
    __shared__ bf16 Ps[4][16][64];   // per-wave P staging [qrow][kv]
    const int b = blockIdx.y >> 4, h = blockIdx.y & 15;
    const int q0 = blockIdx.x * 64;
    const int t = threadIdx.x, w = t >> 6, lane = t & 63;
    const int lr = lane & 15, lg = lane >> 4;
    const bf16* base = qkv + (size_t)b * N * 3072;

    // Q fragments for this wave's 16 rows (A-operand: row=lane&15, k=8*(lane>>4)+i)
    bf16x8 qf[2];
    {
        const bf16* qp = base + (size_t)(q0 + w * 16 + lr) * 3072 + h * 64 + lg * 8;
        qf[0] = *reinterpret_cast<const bf16x8*>(qp);
        qf[1] = *reinterpret_cast<const bf16x8*>(qp + 32);
    }

    float mrow[4] = { -INFINITY, -INFINITY, -INFINITY, -INFINITY };
    float lrow[4] = { 0.f, 0.f, 0.f, 0.f };
    f32x4 oacc[4] = {};
    const float scale = 0.03125f;  // D^-0.5 = 1024^-0.5 (module scales by embedDim!)
    const int sr = t >> 3, sc = (t & 7) * 8;

    for (int kv0 = 0; kv0 < N; kv0 += 64) {
        __syncthreads();
#pragma unroll
        for (int p = 0; p < 2; ++p) {
            int row = p * 32 + sr;
            *reinterpret_cast<uint4*>(&Ks[row][sc]) =
                *reinterpret_cast<const uint4*>(base + (size_t)(kv0 + row) * 3072 + 1024 + h * 64 + sc);
            bf16x8 vv = *reinterpret_cast<const bf16x8*>(base + (size_t)(kv0 + row) * 3072 + 2048 + h * 64 + sc);
#pragma unroll
            for (int e = 0; e < 8; ++e)
                *reinterpret_cast<short*>(&Vt[sc + e][row]) = vv[e];
        }
        __syncthreads();

        // S = Q @ K^T  (B-operand: col=kv=lane&15, k=dh)
        f32x4 s[4] = {};
#pragma unroll
        for (int f = 0; f < 2; ++f)
#pragma unroll
            for (int c = 0; c < 4; ++c) {
                bf16x8 kb = *reinterpret_cast<const bf16x8*>(&Ks[c * 16 + lr][f * 32 + lg * 8]);
                s[c] = __builtin_amdgcn_mfma_f32_16x16x32_bf16(qf[f], kb, s[c], 0, 0, 0);
            }
#pragma unroll
        for (int c = 0; c < 4; ++c)
#pragma unroll
            for (int j = 0; j < 4; ++j) s[c][j] *= scale;

        // online softmax; lane holds rows 4*lg+j, cols 16*c+lr
        float rmax[4], mnew[4], al[4], psum[4];
#pragma unroll
        for (int j = 0; j < 4; ++j)
            rmax[j] = fmaxf(fmaxf(s[0][j], s[1][j]), fmaxf(s[2][j], s[3][j]));
#pragma unroll
        for (int msk = 1; msk < 16; msk <<= 1)
#pragma unroll
            for (int j = 0; j < 4; ++j)
                rmax[j] = fmaxf(rmax[j], __shfl_xor(rmax[j], msk, 64));
#pragma unroll
        for (int j = 0; j < 4; ++j) {
            mnew[j] = fmaxf(mrow[j], rmax[j]);
            al[j] = __expf(mrow[j] - mnew[j]);
            mrow[j] = mnew[j];
            psum[j] = 0.f;
        }
#pragma unroll
        for (int c = 0; c < 4; ++c)
#pragma unroll
            for (int j = 0; j < 4; ++j) {
                float pv = __expf(s[c][j] - mnew[j]);
                psum[j] += pv;
                Ps[w][lg * 4 + j][c * 16 + lr] = __float2bfloat16(pv);
            }
#pragma unroll
        for (int msk = 1; msk < 16; msk <<= 1)
#pragma unroll
            for (int j = 0; j < 4; ++j)
                psum[j] += __shfl_xor(psum[j], msk, 64);
#pragma unroll
        for (int j = 0; j < 4; ++j) lrow[j] = lrow[j] * al[j] + psum[j];
#pragma unroll
        for (int c = 0; c < 4; ++c)
#pragma unroll
            for (int j = 0; j < 4; ++j) oacc[c][j] *= al[j];

        asm volatile("s_waitcnt lgkmcnt(0)" ::: "memory");  // Ps writes visible in-wave

        // O += P @ V  (A: P rows, B: V^T from Vt)
#pragma unroll
        for (int f = 0; f < 2; ++f) {
            bf16x8 pf = *reinterpret_cast<const bf16x8*>(&Ps[w][lr][f * 32 + lg * 8]);
#pragma unroll
            for (int c = 0; c < 4; ++c) {
                bf16x8 vb = *reinterpret_cast<const bf16x8*>(&Vt[c * 16 + lr][f * 32 + lg * 8]);
                oacc[c] = __builtin_amdgcn_mfma_f32_16x16x32_bf16(pf, vb, oacc[c], 0, 0, 0);
            }
        }
    }

#pragma unroll
    for (int j = 0; j < 4; ++j) lrow[j] = 1.f / lrow[j];
#pragma unroll
    for (int c = 0; c < 4; ++c)
#pragma unroll
        for (int j = 0; j < 4; ++j) {
            size_t row = (size_t)b * N + q0 + w * 16 + lg * 4 + j;
            o[row * 1024 + h * 64 + c * 16 + lr] = oacc[c][j] * lrow[j];
        }
}

// ---- fused residual + LayerNorm (fp32), optional bf16 copy -----------------
__global__ __launch_bounds__(256) void ln_res(const float* __restrict__ a,
                                              const float* __restrict__ r,
                                              const float* __restrict__ g,
                                              const float* __restrict__ be,
                                              float* __restrict__ y,
                                              bf16* __restrict__ yb) {
    const int row = blockIdx.x, t = threadIdx.x;
    float4 va = reinterpret_cast<const float4*>(a + (size_t)row * 1024)[t];
    float4 vr = reinterpret_cast<const float4*>(r + (size_t)row * 1024)[t];
    float v0 = va.x + vr.x, v1 = va.y + vr.y, v2 = va.z + vr.z, v3 = va.w + vr.w;
    float s1 = v0 + v1 + v2 + v3;
    float s2 = v0 * v0 + v1 * v1 + v2 * v2 + v3 * v3;
#pragma unroll
    for (int m = 1; m < 64; m <<= 1) {
        s1 += __shfl_xor(s1, m, 64);
        s2 += __shfl_xor(s2, m, 64);
    }
    __shared__ float ws1[4], ws2[4];
    if ((t & 63) == 0) { ws1[t >> 6] = s1; ws2[t >> 6] = s2; }
    __syncthreads();
    s1 = ws1[0] + ws1[1] + ws1[2] + ws1[3];
    s2 = ws2[0] + ws2[1] + ws2[2] + ws2[3];
    const float mean = s1 * (1.f / 1024.f);
    const float var = s2 * (1.f / 1024.f) - mean * mean;
    const float rstd = rsqrtf(var + 1e-5f);
    float4 gg = reinterpret_cast<const float4*>(g)[t];
    float4 bb = reinterpret_cast<const float4*>(be)[t];
    float o0 = (v0 - mean) * rstd * gg.x + bb.x;
    float o1 = (v1 - mean) * rstd * gg.y + bb.y;
    float o2 = (v2 - mean) * rstd * gg.z + bb.z;
    float o3 = (v3 - mean) * rstd * gg.w + bb.w;
    float4 out = { o0, o1, o2, o3 };
    reinterpret_cast<float4*>(y + (size_t)row * 1024)[t] = out;
    if (yb) {
        ushort4 ob = { f2b(o0), f2b(o1), f2b(o2), f2b(o3) };
        reinterpret_cast<ushort4*>(yb + (size_t)row * 1024)[t] = ob;
    }
}

// ---------------------------------------------------------------------------
extern "C" void kernel_launch(void* const* d_in, const int* in_sizes, int n_in,
                              void* d_out, int out_size, void* d_ws, size_t ws_size,
                              hipStream_t stream) {
    const float* x_in = (const float*)d_in[0];
    const float* Wqkv = (const float*)d_in[1];
    const float* bqkv = (const float*)d_in[2];
    const float* W1   = (const float*)d_in[3];
    const float* b1   = (const float*)d_in[4];
    const float* W2   = (const float*)d_in[5];
    const float* b2   = (const float*)d_in[6];
    const float* g1   = (const float*)d_in[7];
    const float* be1  = (const float*)d_in[8];
    const float* g2   = (const float*)d_in[9];
    const float* be2  = (const float*)d_in[10];

    const int Bv = 2, N = 2048, L = 4, Hh = 16;
    const int R = Bv * N;  // 4096 token rows

    char* p = (char*)d_ws;
    auto alloc = [&](size_t bytes) { char* r = p; p += (bytes + 255) & ~(size_t)255; return r; };
    bf16*  Wqkvt = (bf16*)alloc((size_t)L * 3072 * 1024 * 2);
    bf16*  W1t   = (bf16*)alloc((size_t)L * 4096 * 1024 * 2);
    bf16*  W2t   = (bf16*)alloc((size_t)L * 1024 * 4096 * 2);
    bf16*  xb    = (bf16*)alloc((size_t)R * 1024 * 2);
    bf16*  qkvb  = (bf16*)alloc((size_t)R * 3072 * 2);
    float* obuf  = (float*)alloc((size_t)R * 1024 * 4);
    float* hbuf  = (float*)alloc((size_t)R * 1024 * 4);
    bf16*  hb    = (bf16*)alloc((size_t)R * 1024 * 2);
    bf16*  f1b   = (bf16*)alloc((size_t)R * 4096 * 2);
    float* xcur  = (float*)alloc((size_t)R * 1024 * 4);
    float* f2buf = obuf;  // obuf dead after LN1 -> reuse for f2

    // weights -> bf16, transposed to [Nm][K]
    transpose_cast<<<dim3(3072 / 32, 1024 / 32, L), dim3(32, 8), 0, stream>>>(Wqkv, Wqkvt, 1024, 3072);
    transpose_cast<<<dim3(4096 / 32, 1024 / 32, L), dim3(32, 8), 0, stream>>>(W1, W1t, 1024, 4096);
    transpose_cast<<<dim3(1024 / 32, 4096 / 32, L), dim3(32, 8), 0, stream>>>(W2, W2t, 4096, 1024);
    cast_bf16_k<<<(R * 1024 / 4 + 255) / 256, 256, 0, stream>>>(x_in, xb, R * 1024 / 4);

    const float* xres = x_in;
    for (int l = 0; l < L; ++l) {
        // qkv = x @ Wqkv + bqkv  -> bf16
        gemm_bf16<0><<<dim3(3072 / 128, R / 128), 256, 0, stream>>>(
            xb, Wqkvt + (size_t)l * 3072 * 1024, bqkv + l * 3072, qkvb, R, 3072, 1024);
        // o = softmax(q k^T / 32) v
        attn_fwd<<<dim3(N / 64, Bv * Hh), 256, 0, stream>>>(qkvb, obuf, N);
        // h = LN(o + x)
        ln_res<<<R, 256, 0, stream>>>(obuf, xres, g1 + l * 1024, be1 + l * 1024, hbuf, hb);
        // f1 = gelu(h @ W1 + b1) -> bf16
        gemm_bf16<1><<<dim3(4096 / 128, R / 128), 256, 0, stream>>>(
            hb, W1t + (size_t)l * 4096 * 1024, b1 + l * 4096, f1b, R, 4096, 1024);
        // f2 = gelu(f1 @ W2 + b2) -> fp32
        gemm_bf16<2><<<dim3(1024 / 128, R / 128), 256, 0, stream>>>(
            f1b, W2t + (size_t)l * 1024 * 4096, b2 + l * 1024, f2buf, R, 1024, 4096);
        // x = LN(f2 + h), also emit bf16 copy for next layer's GEMM
        float* xn = (l == L - 1) ? (float*)d_out : xcur;
        ln_res<<<R, 256, 0, stream>>>(f2buf, hbuf, g2 + l * 1024, be2 + l * 1024, xn, xb);
        xres = xn;
    }
}

// Round 2
// 1448.916 us; speedup vs baseline: 1.0809x; 1.0809x over previous
//
#include <hip/hip_runtime.h>
#include <hip/hip_bf16.h>
#include <cmath>

// ---------------------------------------------------------------------------
// TextEncoder: 4-layer post-LN transformer, B=2 N=2048 D=1024 H=16 dh=64 FF=4096
// R1: GEMM -> m97 pattern (global_load_lds w16, linear LDS). Attention -> global
// V-transpose (kills the 16-way scatter conflict), padded Ps, 32 q-rows/wave.
// ---------------------------------------------------------------------------

typedef __attribute__((ext_vector_type(8))) short bf16x8;
typedef __attribute__((ext_vector_type(4))) float f32x4;
typedef __hip_bfloat16 bf16;

#define DEV static __device__ __forceinline__

DEV unsigned short f2b(float f) {
    bf16 h = __float2bfloat16(f);
    return *reinterpret_cast<unsigned short*>(&h);
}

DEV float gelu_exact(float x) {
    return 0.5f * x * (1.0f + erff(x * 0.70710678118654752440f));
}

DEV void gload_lds16(const bf16* g, bf16* l) {
    __builtin_amdgcn_global_load_lds(
        (const __attribute__((address_space(1))) void*)g,
        (__attribute__((address_space(3))) void*)l, 16, 0, 0);
}

// ---- weight transpose + cast: Wt[l][n][k] = (bf16) W[l][k][n] --------------
__global__ __launch_bounds__(256) void transpose_cast(const float* __restrict__ W,
                                                      bf16* __restrict__ Wt,
                                                      int K, int Nm) {
    __shared__ float tile[32][33];
    const int l = blockIdx.z;
    const float* Wl = W + (size_t)l * K * Nm;
    bf16* Wtl = Wt + (size_t)l * K * Nm;
    const int n0 = blockIdx.x * 32, k0 = blockIdx.y * 32;
    const int tx = threadIdx.x, ty = threadIdx.y;
#pragma unroll
    for (int i = 0; i < 4; ++i)
        tile[ty + 8 * i][tx] = Wl[(size_t)(k0 + ty + 8 * i) * Nm + n0 + tx];
    __syncthreads();
#pragma unroll
    for (int i = 0; i < 4; ++i)
        Wtl[(size_t)(n0 + ty + 8 * i) * K + k0 + tx] = __float2bfloat16(tile[tx][ty + 8 * i]);
}

// ---- V transpose: qkv[b,n,2048+h*64+d] -> vtg[(b*16+h)*64+d][n]  (bf16) ----
__global__ __launch_bounds__(256) void vtrans(const bf16* __restrict__ qkv,
                                              bf16* __restrict__ vtg, int N) {
    __shared__ bf16 tile[32][33];
    const int bh = blockIdx.z, b = bh >> 4, h = bh & 15;
    const int n0 = blockIdx.x * 32, d0 = blockIdx.y * 32;
    const int tx = threadIdx.x, ty = threadIdx.y;
    const bf16* src = qkv + (size_t)(b * N + n0) * 3072 + 2048 + h * 64 + d0;
#pragma unroll
    for (int i = 0; i < 4; ++i)
        tile[ty + 8 * i][tx] = src[(size_t)(ty + 8 * i) * 3072 + tx];
    __syncthreads();
    bf16* dst = vtg + ((size_t)bh * 64 + d0) * N + n0;
#pragma unroll
    for (int i = 0; i < 4; ++i)
        dst[(size_t)(ty + 8 * i) * N + tx] = tile[tx][ty + 8 * i];
}

// ---- elementwise fp32 -> bf16 ----------------------------------------------
__global__ __launch_bounds__(256) void cast_bf16_k(const float* __restrict__ in,
                                                   bf16* __restrict__ out, int n4) {
    int i = blockIdx.x * 256 + threadIdx.x;
    if (i >= n4) return;
    float4 v = reinterpret_cast<const float4*>(in)[i];
    ushort4 o = { f2b(v.x), f2b(v.y), f2b(v.z), f2b(v.w) };
    reinterpret_cast<ushort4*>(out)[i] = o;
}

// ---- bf16 MFMA GEMM (m97 pattern): C[M,Nm] = A[M,K] @ Bt[Nm,K]^T + bias ----
// EPI: 0 = bias -> bf16 out; 1 = bias+gelu -> bf16 out; 2 = bias+gelu -> f32 out
template <int EPI>
__global__ __launch_bounds__(256) void gemm_bf16(const bf16* __restrict__ A,
                                                 const bf16* __restrict__ Bt,
                                                 const float* __restrict__ bias,
                                                 void* __restrict__ Cout,
                                                 int M, int Nm, int K) {
    __shared__ bf16 As[128][64];  // linear: required by global_load_lds
    __shared__ bf16 Bs[128][64];
    const int m0 = blockIdx.y * 128, n0 = blockIdx.x * 128;
    const int t = threadIdx.x, w = t >> 6, lane = t & 63;
    const int wr = (w >> 1) * 64, wc = (w & 1) * 64;
    const int lr = lane & 15, lg = lane >> 4;
    const int srowbase = w * 32;          // wave stages 32 rows of A and of B
    const int slrow = lane >> 3;          // row within 8-row chunk
    const int scol = (lane & 7) * 8;      // bf16 col of this lane's 16B

    f32x4 acc[4][4] = {};

    for (int k0 = 0; k0 < K; k0 += 64) {
        __syncthreads();  // previous tile's reads done before overwrite
#pragma unroll
        for (int p = 0; p < 4; ++p) {
            const int r = srowbase + p * 8;
            gload_lds16(A + (size_t)(m0 + r + slrow) * K + k0 + scol, &As[r][0]);
            gload_lds16(Bt + (size_t)(n0 + r + slrow) * K + k0 + scol, &Bs[r][0]);
        }
        __syncthreads();  // compiler drains vmcnt before barrier
#pragma unroll
        for (int kk = 0; kk < 2; ++kk) {
            const int lk = kk * 32 + lg * 8;
            bf16x8 a[4], b[4];
#pragma unroll
            for (int m = 0; m < 4; ++m)
                a[m] = *reinterpret_cast<const bf16x8*>(&As[wr + m * 16 + lr][lk]);
#pragma unroll
            for (int n = 0; n < 4; ++n)
                b[n] = *reinterpret_cast<const bf16x8*>(&Bs[wc + n * 16 + lr][lk]);
#pragma unroll
            for (int m = 0; m < 4; ++m)
#pragma unroll
                for (int n = 0; n < 4; ++n)
                    acc[m][n] = __builtin_amdgcn_mfma_f32_16x16x32_bf16(a[m], b[n], acc[m][n], 0, 0, 0);
        }
    }

    // epilogue: D layout col = lane&15, row = (lane>>4)*4 + j
#pragma unroll
    for (int n = 0; n < 4; ++n) {
        const int col = n0 + wc + n * 16 + lr;
        const float bc = bias[col];
#pragma unroll
        for (int m = 0; m < 4; ++m) {
            const int row = m0 + wr + m * 16 + lg * 4;
#pragma unroll
            for (int j = 0; j < 4; ++j) {
                float v = acc[m][n][j] + bc;
                if (EPI >= 1) v = gelu_exact(v);
                if (EPI == 2)
                    reinterpret_cast<float*>(Cout)[(size_t)(row + j) * Nm + col] = v;
                else
                    reinterpret_cast<bf16*>(Cout)[(size_t)(row + j) * Nm + col] = __float2bfloat16(v);
            }
        }
    }
}

// ---- flash attention: Q,K from qkv; V^T from vtg; o fp32 [B*N, 1024] -------
// grid (N/128, B*H), block 256 (4 waves); each wave owns 32 q-rows, KVBLK=64.
__global__ __launch_bounds__(256) void attn_fwd(const bf16* __restrict__ qkv,
                                                const bf16* __restrict__ vtg,
                                                float* __restrict__ o, int N) {
    __shared__ bf16 Ks[64][72];      // K tile [kv][dh], padded
    __shared__ bf16 Vs[64][72];      // V^T tile [dh][kv], padded
    __shared__ bf16 Ps[4][32][72];   // per-wave P staging [qrow][kv], padded
    const int bh = blockIdx.y, b = bh >> 4, h = bh & 15;
    const int q0 = blockIdx.x * 128;
    const int t = threadIdx.x, w = t >> 6, lane = t & 63;
    const int lr = lane & 15, lg = lane >> 4;
    const bf16* base = qkv + (size_t)b * N * 3072;
    const bf16* vbase = vtg + (size_t)bh * 64 * N;

    // Q fragments: wave w owns rows q0+w*32+rb*16+{0..15}
    bf16x8 qf[2][2];
#pragma unroll
    for (int rb = 0; rb < 2; ++rb) {
        const bf16* qp = base + (size_t)(q0 + w * 32 + rb * 16 + lr) * 3072 + h * 64 + lg * 8;
        qf[rb][0] = *reinterpret_cast<const bf16x8*>(qp);
        qf[rb][1] = *reinterpret_cast<const bf16x8*>(qp + 32);
    }

    float mrow[2][4], lrow[2][4];
#pragma unroll
    for (int rb = 0; rb < 2; ++rb)
#pragma unroll
        for (int j = 0; j < 4; ++j) { mrow[rb][j] = -INFINITY; lrow[rb][j] = 0.f; }
    f32x4 oacc[2][4] = {};
    const float scale = 0.03125f;  // embedDim^-0.5 = 1024^-0.5
    const int srow = t >> 2, scol = (t & 3) * 8;

    for (int kv0 = 0; kv0 < N; kv0 += 64) {
        __syncthreads();
        {   // stage K [kv][dh] and V^T [dh][kv], vectorized, conflict-free-ish
            const bf16* ksrc = base + (size_t)(kv0 + srow) * 3072 + 1024 + h * 64 + scol;
            *reinterpret_cast<uint4*>(&Ks[srow][scol])      = *reinterpret_cast<const uint4*>(ksrc);
            *reinterpret_cast<uint4*>(&Ks[srow][scol + 32]) = *reinterpret_cast<const uint4*>(ksrc + 32);
            const bf16* vsrc = vbase + (size_t)srow * N + kv0 + scol;
            *reinterpret_cast<uint4*>(&Vs[srow][scol])      = *reinterpret_cast<const uint4*>(vsrc);
            *reinterpret_cast<uint4*>(&Vs[srow][scol + 32]) = *reinterpret_cast<const uint4*>(vsrc + 32);
        }
        __syncthreads();

        // S = Q @ K^T : each kb feeds both row-blocks (2 MFMA per ds_read)
        f32x4 s[2][4] = {};
#pragma unroll
        for (int f = 0; f < 2; ++f)
#pragma unroll
            for (int c = 0; c < 4; ++c) {
                bf16x8 kb = *reinterpret_cast<const bf16x8*>(&Ks[c * 16 + lr][f * 32 + lg * 8]);
                s[0][c] = __builtin_amdgcn_mfma_f32_16x16x32_bf16(qf[0][f], kb, s[0][c], 0, 0, 0);
                s[1][c] = __builtin_amdgcn_mfma_f32_16x16x32_bf16(qf[1][f], kb, s[1][c], 0, 0, 0);
            }

        // online softmax (scale folded into exp via fma); lane: rows rb*16+lg*4+j
#pragma unroll
        for (int rb = 0; rb < 2; ++rb) {
            float rmax[4], mnew[4], al[4], psum[4];
#pragma unroll
            for (int j = 0; j < 4; ++j)
                rmax[j] = fmaxf(fmaxf(s[rb][0][j], s[rb][1][j]), fmaxf(s[rb][2][j], s[rb][3][j]));
#pragma unroll
            for (int msk = 1; msk < 16; msk <<= 1)
#pragma unroll
                for (int j = 0; j < 4; ++j)
                    rmax[j] = fmaxf(rmax[j], __shfl_xor(rmax[j], msk, 64));
#pragma unroll
            for (int j = 0; j < 4; ++j) {
                mnew[j] = fmaxf(mrow[rb][j], rmax[j] * scale);
                al[j] = __expf(mrow[rb][j] - mnew[j]);
                mrow[rb][j] = mnew[j];
                psum[j] = 0.f;
            }
#pragma unroll
            for (int c = 0; c < 4; ++c)
#pragma unroll
                for (int j = 0; j < 4; ++j) {
                    float pv = __expf(fmaf(s[rb][c][j], scale, -mnew[j]));
                    psum[j] += pv;
                    Ps[w][rb * 16 + lg * 4 + j][c * 16 + lr] = __float2bfloat16(pv);
                }
#pragma unroll
            for (int msk = 1; msk < 16; msk <<= 1)
#pragma unroll
                for (int j = 0; j < 4; ++j)
                    psum[j] += __shfl_xor(psum[j], msk, 64);
#pragma unroll
            for (int j = 0; j < 4; ++j) lrow[rb][j] = lrow[rb][j] * al[j] + psum[j];
#pragma unroll
            for (int c = 0; c < 4; ++c)
#pragma unroll
                for (int j = 0; j < 4; ++j) oacc[rb][c][j] *= al[j];
        }

        asm volatile("s_waitcnt lgkmcnt(0)" ::: "memory");  // Ps writes visible in-wave
        __builtin_amdgcn_sched_barrier(0);                   // don't hoist MFMA past it

        // O += P @ V : each vb feeds both row-blocks
#pragma unroll
        for (int f = 0; f < 2; ++f) {
            bf16x8 pf0 = *reinterpret_cast<const bf16x8*>(&Ps[w][lr][f * 32 + lg * 8]);
            bf16x8 pf1 = *reinterpret_cast<const bf16x8*>(&Ps[w][16 + lr][f * 32 + lg * 8]);
#pragma unroll
            for (int c = 0; c < 4; ++c) {
                bf16x8 vb = *reinterpret_cast<const bf16x8*>(&Vs[c * 16 + lr][f * 32 + lg * 8]);
                oacc[0][c] = __builtin_amdgcn_mfma_f32_16x16x32_bf16(pf0, vb, oacc[0][c], 0, 0, 0);
                oacc[1][c] = __builtin_amdgcn_mfma_f32_16x16x32_bf16(pf1, vb, oacc[1][c], 0, 0, 0);
            }
        }
    }

#pragma unroll
    for (int rb = 0; rb < 2; ++rb)
#pragma unroll
        for (int j = 0; j < 4; ++j) {
            const float linv = 1.f / lrow[rb][j];
            const size_t row = (size_t)b * N + q0 + w * 32 + rb * 16 + lg * 4 + j;
#pragma unroll
            for (int c = 0; c < 4; ++c)
                o[row * 1024 + h * 64 + c * 16 + lr] = oacc[rb][c][j] * linv;
        }
}

// ---- fused residual + LayerNorm (fp32), optional bf16 copy -----------------
__global__ __launch_bounds__(256) void ln_res(const float* __restrict__ a,
                                              const float* __restrict__ r,
                                              const float* __restrict__ g,
                                              const float* __restrict__ be,
                                              float* __restrict__ y,
                                              bf16* __restrict__ yb) {
    const int row = blockIdx.x, t = threadIdx.x;
    float4 va = reinterpret_cast<const float4*>(a + (size_t)row * 1024)[t];
    float4 vr = reinterpret_cast<const float4*>(r + (size_t)row * 1024)[t];
    float v0 = va.x + vr.x, v1 = va.y + vr.y, v2 = va.z + vr.z, v3 = va.w + vr.w;
    float s1 = v0 + v1 + v2 + v3;
    float s2 = v0 * v0 + v1 * v1 + v2 * v2 + v3 * v3;
#pragma unroll
    for (int m = 1; m < 64; m <<= 1) {
        s1 += __shfl_xor(s1, m, 64);
        s2 += __shfl_xor(s2, m, 64);
    }
    __shared__ float ws1[4], ws2[4];
    if ((t & 63) == 0) { ws1[t >> 6] = s1; ws2[t >> 6] = s2; }
    __syncthreads();
    s1 = ws1[0] + ws1[1] + ws1[2] + ws1[3];
    s2 = ws2[0] + ws2[1] + ws2[2] + ws2[3];
    const float mean = s1 * (1.f / 1024.f);
    const float var = s2 * (1.f / 1024.f) - mean * mean;
    const float rstd = rsqrtf(var + 1e-5f);
    float4 gg = reinterpret_cast<const float4*>(g)[t];
    float4 bb = reinterpret_cast<const float4*>(be)[t];
    float o0 = (v0 - mean) * rstd * gg.x + bb.x;
    float o1 = (v1 - mean) * rstd * gg.y + bb.y;
    float o2 = (v2 - mean) * rstd * gg.z + bb.z;
    float o3 = (v3 - mean) * rstd * gg.w + bb.w;
    float4 out = { o0, o1, o2, o3 };
    reinterpret_cast<float4*>(y + (size_t)row * 1024)[t] = out;
    if (yb) {
        ushort4 ob = { f2b(o0), f2b(o1), f2b(o2), f2b(o3) };
        reinterpret_cast<ushort4*>(yb + (size_t)row * 1024)[t] = ob;
    }
}

// ---------------------------------------------------------------------------
extern "C" void kernel_launch(void* const* d_in, const int* in_sizes, int n_in,
                              void* d_out, int out_size, void* d_ws, size_t ws_size,
                              hipStream_t stream) {
    const float* x_in = (const float*)d_in[0];
    const float* Wqkv = (const float*)d_in[1];
    const float* bqkv = (const float*)d_in[2];
    const float* W1   = (const float*)d_in[3];
    const float* b1   = (const float*)d_in[4];
    const float* W2   = (const float*)d_in[5];
    const float* b2   = (const float*)d_in[6];
    const float* g1   = (const float*)d_in[7];
    const float* be1  = (const float*)d_in[8];
    const float* g2   = (const float*)d_in[9];
    const float* be2  = (const float*)d_in[10];

    const int Bv = 2, N = 2048, L = 4, Hh = 16;
    const int R = Bv * N;  // 4096 token rows

    char* p = (char*)d_ws;
    auto alloc = [&](size_t bytes) { char* r = p; p += (bytes + 255) & ~(size_t)255; return r; };
    bf16*  Wqkvt = (bf16*)alloc((size_t)L * 3072 * 1024 * 2);
    bf16*  W1t   = (bf16*)alloc((size_t)L * 4096 * 1024 * 2);
    bf16*  W2t   = (bf16*)alloc((size_t)L * 1024 * 4096 * 2);
    bf16*  xb    = (bf16*)alloc((size_t)R * 1024 * 2);
    bf16*  qkvb  = (bf16*)alloc((size_t)R * 3072 * 2);
    float* obuf  = (float*)alloc((size_t)R * 1024 * 4);
    float* hbuf  = (float*)alloc((size_t)R * 1024 * 4);
    bf16*  hb    = (bf16*)alloc((size_t)R * 1024 * 2);
    bf16*  f1b   = (bf16*)alloc((size_t)R * 4096 * 2);
    float* xcur  = (float*)alloc((size_t)R * 1024 * 4);
    float* f2buf = obuf;       // obuf dead after LN1 -> reuse for f2
    bf16*  vtg   = (bf16*)hbuf;  // 8.4MB V^T; hbuf region dead during qkv-gemm/attn

    transpose_cast<<<dim3(3072 / 32, 1024 / 32, L), dim3(32, 8), 0, stream>>>(Wqkv, Wqkvt, 1024, 3072);
    transpose_cast<<<dim3(4096 / 32, 1024 / 32, L), dim3(32, 8), 0, stream>>>(W1, W1t, 1024, 4096);
    transpose_cast<<<dim3(1024 / 32, 4096 / 32, L), dim3(32, 8), 0, stream>>>(W2, W2t, 4096, 1024);
    cast_bf16_k<<<(R * 1024 / 4 + 255) / 256, 256, 0, stream>>>(x_in, xb, R * 1024 / 4);

    const float* xres = x_in;
    for (int l = 0; l < L; ++l) {
        // qkv = x @ Wqkv + bqkv  -> bf16
        gemm_bf16<0><<<dim3(3072 / 128, R / 128), 256, 0, stream>>>(
            xb, Wqkvt + (size_t)l * 3072 * 1024, bqkv + l * 3072, qkvb, R, 3072, 1024);
        // V^T per (b,h): [dh][N]
        vtrans<<<dim3(N / 32, 2, Bv * Hh), dim3(32, 8), 0, stream>>>(qkvb, vtg, N);
        // o = softmax(q k^T / 32) v
        attn_fwd<<<dim3(N / 128, Bv * Hh), 256, 0, stream>>>(qkvb, vtg, obuf, N);
        // h = LN(o + x)   (overwrites vtg region -- attn already done)
        ln_res<<<R, 256, 0, stream>>>(obuf, xres, g1 + l * 1024, be1 + l * 1024, hbuf, hb);
        // f1 = gelu(h @ W1 + b1) -> bf16
        gemm_bf16<1><<<dim3(4096 / 128, R / 128), 256, 0, stream>>>(
            hb, W1t + (size_t)l * 4096 * 1024, b1 + l * 4096, f1b, R, 4096, 1024);
        // f2 = gelu(f1 @ W2 + b2) -> fp32
        gemm_bf16<2><<<dim3(1024 / 128, R / 128), 256, 0, stream>>>(
            f1b, W2t + (size_t)l * 1024 * 4096, b2 + l * 1024, f2buf, R, 1024, 4096);
        // x = LN(f2 + h), also emit bf16 copy for next layer's GEMM
        float* xn = (l == L - 1) ? (float*)d_out : xcur;
        ln_res<<<R, 256, 0, stream>>>(f2buf, hbuf, g2 + l * 1024, be2 + l * 1024, xn, xb);
        xres = xn;
    }
}

// Round 4
// 1350.485 us; speedup vs baseline: 1.1597x; 1.0729x over previous
//
#include <hip/hip_runtime.h>
#include <hip/hip_bf16.h>
#include <cmath>

// ---------------------------------------------------------------------------
// TextEncoder: 4-layer post-LN transformer, B=2 N=2048 D=1024 H=16 dh=64 FF=4096
// R3: R2 structure (swapped QK^T, lane-local softmax, in-register P^T relayout)
// with the cvt_pk inline-asm replaced by explicit bf16 packing (the R2 failure
// was consistent with swapped lo/hi packing in v_cvt_pk_bf16_f32).
// ---------------------------------------------------------------------------

typedef __attribute__((ext_vector_type(8))) short bf16x8;
typedef __attribute__((ext_vector_type(4))) float f32x4;
typedef __hip_bfloat16 bf16;

#define DEV static __device__ __forceinline__

DEV unsigned short f2b(float f) {
    bf16 h = __float2bfloat16(f);
    return *reinterpret_cast<unsigned short*>(&h);
}

DEV unsigned int pack_bf16(float lo, float hi) {
    return (unsigned int)f2b(lo) | ((unsigned int)f2b(hi) << 16);
}

DEV float gelu_exact(float x) {
    return 0.5f * x * (1.0f + erff(x * 0.70710678118654752440f));
}

DEV void gload_lds16(const bf16* g, bf16* l) {
    __builtin_amdgcn_global_load_lds(
        (const __attribute__((address_space(1))) void*)g,
        (__attribute__((address_space(3))) void*)l, 16, 0, 0);
}

// ---- weight transpose + cast: Wt[l][n][k] = (bf16) W[l][k][n] --------------
__global__ __launch_bounds__(256) void transpose_cast(const float* __restrict__ W,
                                                      bf16* __restrict__ Wt,
                                                      int K, int Nm) {
    __shared__ float tile[32][33];
    const int l = blockIdx.z;
    const float* Wl = W + (size_t)l * K * Nm;
    bf16* Wtl = Wt + (size_t)l * K * Nm;
    const int n0 = blockIdx.x * 32, k0 = blockIdx.y * 32;
    const int tx = threadIdx.x, ty = threadIdx.y;
#pragma unroll
    for (int i = 0; i < 4; ++i)
        tile[ty + 8 * i][tx] = Wl[(size_t)(k0 + ty + 8 * i) * Nm + n0 + tx];
    __syncthreads();
#pragma unroll
    for (int i = 0; i < 4; ++i)
        Wtl[(size_t)(n0 + ty + 8 * i) * K + k0 + tx] = __float2bfloat16(tile[tx][ty + 8 * i]);
}

// ---- V transpose: qkv[b,n,2048+h*64+d] -> vtg[(b*16+h)*64+d][n]  (bf16) ----
__global__ __launch_bounds__(256) void vtrans(const bf16* __restrict__ qkv,
                                              bf16* __restrict__ vtg, int N) {
    __shared__ bf16 tile[32][33];
    const int bh = blockIdx.z, b = bh >> 4, h = bh & 15;
    const int n0 = blockIdx.x * 32, d0 = blockIdx.y * 32;
    const int tx = threadIdx.x, ty = threadIdx.y;
    const bf16* src = qkv + (size_t)(b * N + n0) * 3072 + 2048 + h * 64 + d0;
#pragma unroll
    for (int i = 0; i < 4; ++i)
        tile[ty + 8 * i][tx] = src[(size_t)(ty + 8 * i) * 3072 + tx];
    __syncthreads();
    bf16* dst = vtg + ((size_t)bh * 64 + d0) * N + n0;
#pragma unroll
    for (int i = 0; i < 4; ++i)
        dst[(size_t)(ty + 8 * i) * N + tx] = tile[tx][ty + 8 * i];
}

// ---- elementwise fp32 -> bf16 ----------------------------------------------
__global__ __launch_bounds__(256) void cast_bf16_k(const float* __restrict__ in,
                                                   bf16* __restrict__ out, int n4) {
    int i = blockIdx.x * 256 + threadIdx.x;
    if (i >= n4) return;
    float4 v = reinterpret_cast<const float4*>(in)[i];
    ushort4 o = { f2b(v.x), f2b(v.y), f2b(v.z), f2b(v.w) };
    reinterpret_cast<ushort4*>(out)[i] = o;
}

// ---- bf16 MFMA GEMM (m97 pattern): C[M,Nm] = A[M,K] @ Bt[Nm,K]^T + bias ----
// 1D grid with XCD-chunked swizzle (nwg % 8 == 0 for all our shapes).
template <int EPI>
__global__ __launch_bounds__(256) void gemm_bf16(const bf16* __restrict__ A,
                                                 const bf16* __restrict__ Bt,
                                                 const float* __restrict__ bias,
                                                 void* __restrict__ Cout,
                                                 int M, int Nm, int K, int nbx) {
    __shared__ bf16 As[128][64];  // linear: required by global_load_lds
    __shared__ bf16 Bs[128][64];
    const int nwg = gridDim.x;
    int id = blockIdx.x;
    if ((nwg & 7) == 0) id = (id & 7) * (nwg >> 3) + (id >> 3);  // XCD-chunked
    const int m0 = (id / nbx) * 128, n0 = (id % nbx) * 128;
    const int t = threadIdx.x, w = t >> 6, lane = t & 63;
    const int wr = (w >> 1) * 64, wc = (w & 1) * 64;
    const int lr = lane & 15, lg = lane >> 4;
    const int srowbase = w * 32;
    const int slrow = lane >> 3;
    const int scol = (lane & 7) * 8;

    f32x4 acc[4][4] = {};

    for (int k0 = 0; k0 < K; k0 += 64) {
        __syncthreads();
#pragma unroll
        for (int p = 0; p < 4; ++p) {
            const int r = srowbase + p * 8;
            gload_lds16(A + (size_t)(m0 + r + slrow) * K + k0 + scol, &As[r][0]);
            gload_lds16(Bt + (size_t)(n0 + r + slrow) * K + k0 + scol, &Bs[r][0]);
        }
        __syncthreads();
#pragma unroll
        for (int kk = 0; kk < 2; ++kk) {
            const int lk = kk * 32 + lg * 8;
            bf16x8 a[4], b[4];
#pragma unroll
            for (int m = 0; m < 4; ++m)
                a[m] = *reinterpret_cast<const bf16x8*>(&As[wr + m * 16 + lr][lk]);
#pragma unroll
            for (int n = 0; n < 4; ++n)
                b[n] = *reinterpret_cast<const bf16x8*>(&Bs[wc + n * 16 + lr][lk]);
#pragma unroll
            for (int m = 0; m < 4; ++m)
#pragma unroll
                for (int n = 0; n < 4; ++n)
                    acc[m][n] = __builtin_amdgcn_mfma_f32_16x16x32_bf16(a[m], b[n], acc[m][n], 0, 0, 0);
        }
    }

#pragma unroll
    for (int n = 0; n < 4; ++n) {
        const int col = n0 + wc + n * 16 + lr;
        const float bc = bias[col];
#pragma unroll
        for (int m = 0; m < 4; ++m) {
            const int row = m0 + wr + m * 16 + lg * 4;
#pragma unroll
            for (int j = 0; j < 4; ++j) {
                float v = acc[m][n][j] + bc;
                if (EPI >= 1) v = gelu_exact(v);
                if (EPI == 2)
                    reinterpret_cast<float*>(Cout)[(size_t)(row + j) * Nm + col] = v;
                else
                    reinterpret_cast<bf16*>(Cout)[(size_t)(row + j) * Nm + col] = __float2bfloat16(v);
            }
        }
    }
}

// ---- flash attention, swapped-operand form ---------------------------------
// grid 1D (N/64)*(B*H) swizzled; block 256 (4 waves); each wave owns 16 q-rows.
// S^T = mfma(K, Q): lane holds q=lr, kv=16c+4lg+j -> lane-local softmax.
// PV: O^T = mfma(V^T, P^T); P^T B-frag built in-register via shfl+select.
__global__ __launch_bounds__(256) void attn_fwd(const bf16* __restrict__ qkv,
                                                const bf16* __restrict__ vtg,
                                                float* __restrict__ o, int N) {
    __shared__ bf16 Ks[64][72];   // K tile [kv][dh], padded
    __shared__ bf16 Vs[64][72];   // V^T tile [dh][kv], padded
    const int nwg = gridDim.x, nbx = N / 64;
    int id = blockIdx.x;
    id = (id & 7) * (nwg >> 3) + (id >> 3);  // XCD-chunked: 4 heads' K/V per L2
    const int bh = id / nbx, b = bh >> 4, h = bh & 15;
    const int q0 = (id % nbx) * 64;
    const int t = threadIdx.x, w = t >> 6, lane = t & 63;
    const int lr = lane & 15, lg = lane >> 4;
    const bf16* base = qkv + (size_t)b * N * 3072;
    const bf16* vbase = vtg + (size_t)bh * 64 * N;

    // Q as B-operand: col q = lr, k = 32f + 8lg + i
    bf16x8 qf[2];
    {
        const bf16* qp = base + (size_t)(q0 + w * 16 + lr) * 3072 + h * 64 + lg * 8;
        qf[0] = *reinterpret_cast<const bf16x8*>(qp);
        qf[1] = *reinterpret_cast<const bf16x8*>(qp + 32);
    }

    float mrow = -INFINITY, lrow = 0.f;
    f32x4 oacc[4] = {};
    const float scale2 = 0.03125f * 1.44269504088896340736f;  // embedDim^-0.5 * log2(e)
    const int srow = t >> 2, scol = (t & 3) * 8;
    const int src0 = ((lane & 16) << 1) | lr;   // 32*(lg&1) + lr
    const int src1 = src0 + 16;
    const bool hic = lane >= 32;                // lg>>1

    for (int kv0 = 0; kv0 < N; kv0 += 64) {
        __syncthreads();
        {   // stage K [kv][dh] and V^T [dh][kv]
            const bf16* ksrc = base + (size_t)(kv0 + srow) * 3072 + 1024 + h * 64 + scol;
            *reinterpret_cast<uint4*>(&Ks[srow][scol])      = *reinterpret_cast<const uint4*>(ksrc);
            *reinterpret_cast<uint4*>(&Ks[srow][scol + 32]) = *reinterpret_cast<const uint4*>(ksrc + 32);
            const bf16* vsrc = vbase + (size_t)srow * N + kv0 + scol;
            *reinterpret_cast<uint4*>(&Vs[srow][scol])      = *reinterpret_cast<const uint4*>(vsrc);
            *reinterpret_cast<uint4*>(&Vs[srow][scol + 32]) = *reinterpret_cast<const uint4*>(vsrc + 32);
        }
        __syncthreads();

        // S^T[kv][q] = K @ Q^T : A = K-frag (rows kv), B = Q-frag (cols q)
        f32x4 st[4] = {};
#pragma unroll
        for (int f = 0; f < 2; ++f)
#pragma unroll
            for (int c = 0; c < 4; ++c) {
                bf16x8 ka = *reinterpret_cast<const bf16x8*>(&Ks[c * 16 + lr][f * 32 + lg * 8]);
                st[c] = __builtin_amdgcn_mfma_f32_16x16x32_bf16(ka, qf[f], st[c], 0, 0, 0);
            }

        // lane-local softmax over this lane's 16 kv values (exp2 domain)
        float smax = st[0][0];
#pragma unroll
        for (int c = 0; c < 4; ++c)
#pragma unroll
            for (int j = 0; j < 4; ++j) smax = fmaxf(smax, st[c][j]);
        smax = fmaxf(smax, __shfl_xor(smax, 16, 64));
        smax = fmaxf(smax, __shfl_xor(smax, 32, 64));
        const float mnew = fmaxf(mrow, smax * scale2);
        const float al = __builtin_amdgcn_exp2f(mrow - mnew);
        mrow = mnew;

        float p[4][4];
        float psum = 0.f;
#pragma unroll
        for (int c = 0; c < 4; ++c)
#pragma unroll
            for (int j = 0; j < 4; ++j) {
                p[c][j] = __builtin_amdgcn_exp2f(fmaf(st[c][j], scale2, -mnew));
                psum += p[c][j];
            }
        psum += __shfl_xor(psum, 16, 64);
        psum += __shfl_xor(psum, 32, 64);
        lrow = lrow * al + psum;
#pragma unroll
        for (int c = 0; c < 4; ++c)
#pragma unroll
            for (int j = 0; j < 4; ++j) oacc[c][j] *= al;

        // pack P -> bf16 pairs: pk[c][u] = (p[c][2u] lo, p[c][2u+1] hi)
        unsigned int pk[4][2];
#pragma unroll
        for (int c = 0; c < 4; ++c) {
            pk[c][0] = pack_bf16(p[c][0], p[c][1]);
            pk[c][1] = pack_bf16(p[c][2], p[c][3]);
        }

        // O^T += V^T @ P^T : per k-chunk f build P^T B-frag via in-wave exchange
        // dest lane (lg,lr) word u <- pk[2f+(lg>>1)][u&1] from lane 32*(lg&1)+16*(u>>1)+lr
#pragma unroll
        for (int f = 0; f < 2; ++f) {
            unsigned int a0 = __shfl((int)pk[2 * f][0], src0, 64);
            unsigned int a1 = __shfl((int)pk[2 * f][1], src0, 64);
            unsigned int a2 = __shfl((int)pk[2 * f][0], src1, 64);
            unsigned int a3 = __shfl((int)pk[2 * f][1], src1, 64);
            unsigned int b0 = __shfl((int)pk[2 * f + 1][0], src0, 64);
            unsigned int b1 = __shfl((int)pk[2 * f + 1][1], src0, 64);
            unsigned int b2 = __shfl((int)pk[2 * f + 1][0], src1, 64);
            unsigned int b3 = __shfl((int)pk[2 * f + 1][1], src1, 64);
            union { unsigned int u[4]; bf16x8 v; } pb;
            pb.u[0] = hic ? b0 : a0;
            pb.u[1] = hic ? b1 : a1;
            pb.u[2] = hic ? b2 : a2;
            pb.u[3] = hic ? b3 : a3;
#pragma unroll
            for (int c = 0; c < 4; ++c) {
                bf16x8 va = *reinterpret_cast<const bf16x8*>(&Vs[c * 16 + lr][f * 32 + lg * 8]);
                oacc[c] = __builtin_amdgcn_mfma_f32_16x16x32_bf16(va, pb.v, oacc[c], 0, 0, 0);
            }
        }
    }

    // O^T layout: col q = lr, row d = 16c + 4lg + j -> float4 stores
    const float linv = 1.f / lrow;
    float* op = o + ((size_t)b * N + q0 + w * 16 + lr) * 1024 + h * 64;
#pragma unroll
    for (int c = 0; c < 4; ++c) {
        float4 v = { oacc[c][0] * linv, oacc[c][1] * linv,
                     oacc[c][2] * linv, oacc[c][3] * linv };
        *reinterpret_cast<float4*>(op + c * 16 + lg * 4) = v;
    }
}

// ---- fused residual + LayerNorm (fp32), optional bf16 copy -----------------
__global__ __launch_bounds__(256) void ln_res(const float* __restrict__ a,
                                              const float* __restrict__ r,
                                              const float* __restrict__ g,
                                              const float* __restrict__ be,
                                              float* __restrict__ y,
                                              bf16* __restrict__ yb) {
    const int row = blockIdx.x, t = threadIdx.x;
    float4 va = reinterpret_cast<const float4*>(a + (size_t)row * 1024)[t];
    float4 vr = reinterpret_cast<const float4*>(r + (size_t)row * 1024)[t];
    float v0 = va.x + vr.x, v1 = va.y + vr.y, v2 = va.z + vr.z, v3 = va.w + vr.w;
    float s1 = v0 + v1 + v2 + v3;
    float s2 = v0 * v0 + v1 * v1 + v2 * v2 + v3 * v3;
#pragma unroll
    for (int m = 1; m < 64; m <<= 1) {
        s1 += __shfl_xor(s1, m, 64);
        s2 += __shfl_xor(s2, m, 64);
    }
    __shared__ float ws1[4], ws2[4];
    if ((t & 63) == 0) { ws1[t >> 6] = s1; ws2[t >> 6] = s2; }
    __syncthreads();
    s1 = ws1[0] + ws1[1] + ws1[2] + ws1[3];
    s2 = ws2[0] + ws2[1] + ws2[2] + ws2[3];
    const float mean = s1 * (1.f / 1024.f);
    const float var = s2 * (1.f / 1024.f) - mean * mean;
    const float rstd = rsqrtf(var + 1e-5f);
    float4 gg = reinterpret_cast<const float4*>(g)[t];
    float4 bb = reinterpret_cast<const float4*>(be)[t];
    float o0 = (v0 - mean) * rstd * gg.x + bb.x;
    float o1 = (v1 - mean) * rstd * gg.y + bb.y;
    float o2 = (v2 - mean) * rstd * gg.z + bb.z;
    float o3 = (v3 - mean) * rstd * gg.w + bb.w;
    float4 out = { o0, o1, o2, o3 };
    reinterpret_cast<float4*>(y + (size_t)row * 1024)[t] = out;
    if (yb) {
        ushort4 ob = { f2b(o0), f2b(o1), f2b(o2), f2b(o3) };
        reinterpret_cast<ushort4*>(yb + (size_t)row * 1024)[t] = ob;
    }
}

// ---------------------------------------------------------------------------
extern "C" void kernel_launch(void* const* d_in, const int* in_sizes, int n_in,
                              void* d_out, int out_size, void* d_ws, size_t ws_size,
                              hipStream_t stream) {
    const float* x_in = (const float*)d_in[0];
    const float* Wqkv = (const float*)d_in[1];
    const float* bqkv = (const float*)d_in[2];
    const float* W1   = (const float*)d_in[3];
    const float* b1   = (const float*)d_in[4];
    const float* W2   = (const float*)d_in[5];
    const float* b2   = (const float*)d_in[6];
    const float* g1   = (const float*)d_in[7];
    const float* be1  = (const float*)d_in[8];
    const float* g2   = (const float*)d_in[9];
    const float* be2  = (const float*)d_in[10];

    const int Bv = 2, N = 2048, L = 4, Hh = 16;
    const int R = Bv * N;  // 4096 token rows

    char* p = (char*)d_ws;
    auto alloc = [&](size_t bytes) { char* r = p; p += (bytes + 255) & ~(size_t)255; return r; };
    bf16*  Wqkvt = (bf16*)alloc((size_t)L * 3072 * 1024 * 2);
    bf16*  W1t   = (bf16*)alloc((size_t)L * 4096 * 1024 * 2);
    bf16*  W2t   = (bf16*)alloc((size_t)L * 1024 * 4096 * 2);
    bf16*  xb    = (bf16*)alloc((size_t)R * 1024 * 2);
    bf16*  qkvb  = (bf16*)alloc((size_t)R * 3072 * 2);
    float* obuf  = (float*)alloc((size_t)R * 1024 * 4);
    float* hbuf  = (float*)alloc((size_t)R * 1024 * 4);
    bf16*  hb    = (bf16*)alloc((size_t)R * 1024 * 2);
    bf16*  f1b   = (bf16*)alloc((size_t)R * 4096 * 2);
    float* xcur  = (float*)alloc((size_t)R * 1024 * 4);
    float* f2buf = obuf;        // obuf dead after LN1 -> reuse for f2
    bf16*  vtg   = (bf16*)hbuf; // 8.4MB V^T; hbuf region dead during qkv-gemm/attn

    transpose_cast<<<dim3(3072 / 32, 1024 / 32, L), dim3(32, 8), 0, stream>>>(Wqkv, Wqkvt, 1024, 3072);
    transpose_cast<<<dim3(4096 / 32, 1024 / 32, L), dim3(32, 8), 0, stream>>>(W1, W1t, 1024, 4096);
    transpose_cast<<<dim3(1024 / 32, 4096 / 32, L), dim3(32, 8), 0, stream>>>(W2, W2t, 4096, 1024);
    cast_bf16_k<<<(R * 1024 / 4 + 255) / 256, 256, 0, stream>>>(x_in, xb, R * 1024 / 4);

    const float* xres = x_in;
    for (int l = 0; l < L; ++l) {
        // qkv = x @ Wqkv + bqkv  -> bf16
        gemm_bf16<0><<<(3072 / 128) * (R / 128), 256, 0, stream>>>(
            xb, Wqkvt + (size_t)l * 3072 * 1024, bqkv + l * 3072, qkvb, R, 3072, 1024, 3072 / 128);
        // V^T per (b,h): [dh][N]
        vtrans<<<dim3(N / 32, 2, Bv * Hh), dim3(32, 8), 0, stream>>>(qkvb, vtg, N);
        // o = softmax(q k^T / 32) v
        attn_fwd<<<(N / 64) * (Bv * Hh), 256, 0, stream>>>(qkvb, vtg, obuf, N);
        // h = LN(o + x)   (overwrites vtg region -- attn already done)
        ln_res<<<R, 256, 0, stream>>>(obuf, xres, g1 + l * 1024, be1 + l * 1024, hbuf, hb);
        // f1 = gelu(h @ W1 + b1) -> bf16
        gemm_bf16<1><<<(4096 / 128) * (R / 128), 256, 0, stream>>>(
            hb, W1t + (size_t)l * 4096 * 1024, b1 + l * 4096, f1b, R, 4096, 1024, 4096 / 128);
        // f2 = gelu(f1 @ W2 + b2) -> fp32
        gemm_bf16<2><<<(1024 / 128) * (R / 128), 256, 0, stream>>>(
            f1b, W2t + (size_t)l * 1024 * 4096, b2 + l * 1024, f2buf, R, 1024, 4096, 1024 / 128);
        // x = LN(f2 + h), also emit bf16 copy for next layer's GEMM
        float* xn = (l == L - 1) ? (float*)d_out : xcur;
        ln_res<<<R, 256, 0, stream>>>(f2buf, hbuf, g2 + l * 1024, be2 + l * 1024, xn, xb);
        xres = xn;
    }
}

// Round 5
// 1245.435 us; speedup vs baseline: 1.2575x; 1.0843x over previous
//
#include <hip/hip_runtime.h>
#include <hip/hip_bf16.h>
#include <cmath>

// ---------------------------------------------------------------------------
// TextEncoder: 4-layer post-LN transformer, B=2 N=2048 D=1024 H=16 dh=64 FF=4096
// R4: (1) GEMM epilogue: erff -> fast tanh-gelu (exp2+rcp, ~10 ops, |err|<1e-3).
//     (2) attn: P^T relayout via per-wave LDS (4x ds_write_b64 + 2x ds_read_b128
//         replaces 16 shfl + 8 select); defer-max (T13, thr=11 in exp2 domain)
//         skips O-rescale + cross-lane max on most kv-tiles.
// ---------------------------------------------------------------------------

typedef __attribute__((ext_vector_type(8))) short bf16x8;
typedef __attribute__((ext_vector_type(4))) float f32x4;
typedef __hip_bfloat16 bf16;

#define DEV static __device__ __forceinline__

DEV unsigned short f2b(float f) {
    bf16 h = __float2bfloat16(f);
    return *reinterpret_cast<unsigned short*>(&h);
}

DEV unsigned int pack_bf16(float lo, float hi) {
    return (unsigned int)f2b(lo) | ((unsigned int)f2b(hi) << 16);
}

// tanh-form gelu: max abs deviation from exact ~1e-3, ~10 VALU ops.
DEV float gelu_fast(float x) {
    float u = 0.7978845608028654f * fmaf(0.044715f * x, x * x, x);
    u = fminf(fmaxf(u, -15.f), 15.f);               // v_med3; keeps exp2 finite
    float t = __builtin_amdgcn_exp2f(u * 2.8853900817779268f);  // e^(2u)
    float th = (t - 1.0f) * __builtin_amdgcn_rcpf(t + 1.0f);    // tanh(u)
    return 0.5f * x * (1.0f + th);
}

DEV void gload_lds16(const bf16* g, bf16* l) {
    __builtin_amdgcn_global_load_lds(
        (const __attribute__((address_space(1))) void*)g,
        (__attribute__((address_space(3))) void*)l, 16, 0, 0);
}

// ---- weight transpose + cast: Wt[l][n][k] = (bf16) W[l][k][n] --------------
__global__ __launch_bounds__(256) void transpose_cast(const float* __restrict__ W,
                                                      bf16* __restrict__ Wt,
                                                      int K, int Nm) {
    __shared__ float tile[32][33];
    const int l = blockIdx.z;
    const float* Wl = W + (size_t)l * K * Nm;
    bf16* Wtl = Wt + (size_t)l * K * Nm;
    const int n0 = blockIdx.x * 32, k0 = blockIdx.y * 32;
    const int tx = threadIdx.x, ty = threadIdx.y;
#pragma unroll
    for (int i = 0; i < 4; ++i)
        tile[ty + 8 * i][tx] = Wl[(size_t)(k0 + ty + 8 * i) * Nm + n0 + tx];
    __syncthreads();
#pragma unroll
    for (int i = 0; i < 4; ++i)
        Wtl[(size_t)(n0 + ty + 8 * i) * K + k0 + tx] = __float2bfloat16(tile[tx][ty + 8 * i]);
}

// ---- V transpose: qkv[b,n,2048+h*64+d] -> vtg[(b*16+h)*64+d][n]  (bf16) ----
__global__ __launch_bounds__(256) void vtrans(const bf16* __restrict__ qkv,
                                              bf16* __restrict__ vtg, int N) {
    __shared__ bf16 tile[32][33];
    const int bh = blockIdx.z, b = bh >> 4, h = bh & 15;
    const int n0 = blockIdx.x * 32, d0 = blockIdx.y * 32;
    const int tx = threadIdx.x, ty = threadIdx.y;
    const bf16* src = qkv + (size_t)(b * N + n0) * 3072 + 2048 + h * 64 + d0;
#pragma unroll
    for (int i = 0; i < 4; ++i)
        tile[ty + 8 * i][tx] = src[(size_t)(ty + 8 * i) * 3072 + tx];
    __syncthreads();
    bf16* dst = vtg + ((size_t)bh * 64 + d0) * N + n0;
#pragma unroll
    for (int i = 0; i < 4; ++i)
        dst[(size_t)(ty + 8 * i) * N + tx] = tile[tx][ty + 8 * i];
}

// ---- elementwise fp32 -> bf16 ----------------------------------------------
__global__ __launch_bounds__(256) void cast_bf16_k(const float* __restrict__ in,
                                                   bf16* __restrict__ out, int n4) {
    int i = blockIdx.x * 256 + threadIdx.x;
    if (i >= n4) return;
    float4 v = reinterpret_cast<const float4*>(in)[i];
    ushort4 o = { f2b(v.x), f2b(v.y), f2b(v.z), f2b(v.w) };
    reinterpret_cast<ushort4*>(out)[i] = o;
}

// ---- bf16 MFMA GEMM (m97 pattern): C[M,Nm] = A[M,K] @ Bt[Nm,K]^T + bias ----
// 1D grid with XCD-chunked swizzle (nwg % 8 == 0 for all our shapes).
template <int EPI>
__global__ __launch_bounds__(256) void gemm_bf16(const bf16* __restrict__ A,
                                                 const bf16* __restrict__ Bt,
                                                 const float* __restrict__ bias,
                                                 void* __restrict__ Cout,
                                                 int M, int Nm, int K, int nbx) {
    __shared__ bf16 As[128][64];  // linear: required by global_load_lds
    __shared__ bf16 Bs[128][64];
    const int nwg = gridDim.x;
    int id = blockIdx.x;
    if ((nwg & 7) == 0) id = (id & 7) * (nwg >> 3) + (id >> 3);  // XCD-chunked
    const int m0 = (id / nbx) * 128, n0 = (id % nbx) * 128;
    const int t = threadIdx.x, w = t >> 6, lane = t & 63;
    const int wr = (w >> 1) * 64, wc = (w & 1) * 64;
    const int lr = lane & 15, lg = lane >> 4;
    const int srowbase = w * 32;
    const int slrow = lane >> 3;
    const int scol = (lane & 7) * 8;

    f32x4 acc[4][4] = {};

    for (int k0 = 0; k0 < K; k0 += 64) {
        __syncthreads();
#pragma unroll
        for (int p = 0; p < 4; ++p) {
            const int r = srowbase + p * 8;
            gload_lds16(A + (size_t)(m0 + r + slrow) * K + k0 + scol, &As[r][0]);
            gload_lds16(Bt + (size_t)(n0 + r + slrow) * K + k0 + scol, &Bs[r][0]);
        }
        __syncthreads();
#pragma unroll
        for (int kk = 0; kk < 2; ++kk) {
            const int lk = kk * 32 + lg * 8;
            bf16x8 a[4], b[4];
#pragma unroll
            for (int m = 0; m < 4; ++m)
                a[m] = *reinterpret_cast<const bf16x8*>(&As[wr + m * 16 + lr][lk]);
#pragma unroll
            for (int n = 0; n < 4; ++n)
                b[n] = *reinterpret_cast<const bf16x8*>(&Bs[wc + n * 16 + lr][lk]);
#pragma unroll
            for (int m = 0; m < 4; ++m)
#pragma unroll
                for (int n = 0; n < 4; ++n)
                    acc[m][n] = __builtin_amdgcn_mfma_f32_16x16x32_bf16(a[m], b[n], acc[m][n], 0, 0, 0);
        }
    }

#pragma unroll
    for (int n = 0; n < 4; ++n) {
        const int col = n0 + wc + n * 16 + lr;
        const float bc = bias[col];
#pragma unroll
        for (int m = 0; m < 4; ++m) {
            const int row = m0 + wr + m * 16 + lg * 4;
#pragma unroll
            for (int j = 0; j < 4; ++j) {
                float v = acc[m][n][j] + bc;
                if (EPI >= 1) v = gelu_fast(v);
                if (EPI == 2)
                    reinterpret_cast<float*>(Cout)[(size_t)(row + j) * Nm + col] = v;
                else
                    reinterpret_cast<bf16*>(Cout)[(size_t)(row + j) * Nm + col] = __float2bfloat16(v);
            }
        }
    }
}

// ---- flash attention, swapped-operand form ---------------------------------
// grid 1D (N/64)*(B*H) swizzled; block 256 (4 waves); each wave owns 16 q-rows.
// S^T = mfma(K, Q): lane holds q=lr, kv=16c+4lg+j -> lane-local softmax.
// PV: O^T = mfma(V^T, P^T); P^T routed through per-wave LDS tile Ps[q][kv].
__global__ __launch_bounds__(256) void attn_fwd(const bf16* __restrict__ qkv,
                                                const bf16* __restrict__ vtg,
                                                float* __restrict__ o, int N) {
    __shared__ bf16 Ks[64][72];      // K tile [kv][dh], padded
    __shared__ bf16 Vs[64][72];      // V^T tile [dh][kv], padded
    __shared__ bf16 Ps[4][16][72];   // per-wave P [q][kv], padded
    const int nwg = gridDim.x, nbx = N / 64;
    int id = blockIdx.x;
    id = (id & 7) * (nwg >> 3) + (id >> 3);  // XCD-chunked: 4 heads' K/V per L2
    const int bh = id / nbx, b = bh >> 4, h = bh & 15;
    const int q0 = (id % nbx) * 64;
    const int t = threadIdx.x, w = t >> 6, lane = t & 63;
    const int lr = lane & 15, lg = lane >> 4;
    const bf16* base = qkv + (size_t)b * N * 3072;
    const bf16* vbase = vtg + (size_t)bh * 64 * N;

    // Q as B-operand: col q = lr, k = 32f + 8lg + i
    bf16x8 qf[2];
    {
        const bf16* qp = base + (size_t)(q0 + w * 16 + lr) * 3072 + h * 64 + lg * 8;
        qf[0] = *reinterpret_cast<const bf16x8*>(qp);
        qf[1] = *reinterpret_cast<const bf16x8*>(qp + 32);
    }

    float mrow = -INFINITY, lrow = 0.f;
    f32x4 oacc[4] = {};
    const float scale2 = 0.03125f * 1.44269504088896340736f;  // embedDim^-0.5 * log2(e)
    const int srow = t >> 2, scol = (t & 3) * 8;

    for (int kv0 = 0; kv0 < N; kv0 += 64) {
        __syncthreads();
        {   // stage K [kv][dh] and V^T [dh][kv]
            const bf16* ksrc = base + (size_t)(kv0 + srow) * 3072 + 1024 + h * 64 + scol;
            *reinterpret_cast<uint4*>(&Ks[srow][scol])      = *reinterpret_cast<const uint4*>(ksrc);
            *reinterpret_cast<uint4*>(&Ks[srow][scol + 32]) = *reinterpret_cast<const uint4*>(ksrc + 32);
            const bf16* vsrc = vbase + (size_t)srow * N + kv0 + scol;
            *reinterpret_cast<uint4*>(&Vs[srow][scol])      = *reinterpret_cast<const uint4*>(vsrc);
            *reinterpret_cast<uint4*>(&Vs[srow][scol + 32]) = *reinterpret_cast<const uint4*>(vsrc + 32);
        }
        __syncthreads();

        // S^T[kv][q] = K @ Q^T : A = K-frag (rows kv), B = Q-frag (cols q)
        f32x4 st[4] = {};
#pragma unroll
        for (int f = 0; f < 2; ++f)
#pragma unroll
            for (int c = 0; c < 4; ++c) {
                bf16x8 ka = *reinterpret_cast<const bf16x8*>(&Ks[c * 16 + lr][f * 32 + lg * 8]);
                st[c] = __builtin_amdgcn_mfma_f32_16x16x32_bf16(ka, qf[f], st[c], 0, 0, 0);
            }

        // lane-local max over this lane's 16 kv values (exp2 domain)
        float smax = st[0][0];
#pragma unroll
        for (int c = 0; c < 4; ++c)
#pragma unroll
            for (int j = 0; j < 4; ++j) smax = fmaxf(smax, st[c][j]);
        const float tilemax = smax * scale2;

        // defer-max (T13): rescale only when some lane exceeds mrow by >11
        // (P bounded by 2^11 = 2048 -- fine in bf16/fp32 accumulation)
        if (!__all(tilemax - mrow <= 11.0f)) {
            float tm = fmaxf(tilemax, __shfl_xor(tilemax, 16, 64));
            tm = fmaxf(tm, __shfl_xor(tm, 32, 64));   // uniform across lg for fixed q
            const float mnew = fmaxf(mrow, tm);
            const float al = __builtin_amdgcn_exp2f(mrow - mnew);
            mrow = mnew;
            lrow *= al;
#pragma unroll
            for (int c = 0; c < 4; ++c)
#pragma unroll
                for (int j = 0; j < 4; ++j) oacc[c][j] *= al;
        }

        float p[4][4];
        float psum = 0.f;
#pragma unroll
        for (int c = 0; c < 4; ++c)
#pragma unroll
            for (int j = 0; j < 4; ++j) {
                p[c][j] = __builtin_amdgcn_exp2f(fmaf(st[c][j], scale2, -mrow));
                psum += p[c][j];
            }
        psum += __shfl_xor(psum, 16, 64);
        psum += __shfl_xor(psum, 32, 64);
        lrow += psum;

        // write P to per-wave LDS: lane holds P[q=lr][kv=16c+4lg+{0..3}]
#pragma unroll
        for (int c = 0; c < 4; ++c) {
            uint2 pr = { pack_bf16(p[c][0], p[c][1]), pack_bf16(p[c][2], p[c][3]) };
            *reinterpret_cast<uint2*>(&Ps[w][lr][c * 16 + lg * 4]) = pr;
        }
        asm volatile("s_waitcnt lgkmcnt(0)" ::: "memory");  // in-wave write->read
        __builtin_amdgcn_sched_barrier(0);

        // O^T += V^T @ P^T : B-frag col q=lr, k = f*32+lg*8+i -> Ps[lr][...]
#pragma unroll
        for (int f = 0; f < 2; ++f) {
            bf16x8 pb = *reinterpret_cast<const bf16x8*>(&Ps[w][lr][f * 32 + lg * 8]);
#pragma unroll
            for (int c = 0; c < 4; ++c) {
                bf16x8 va = *reinterpret_cast<const bf16x8*>(&Vs[c * 16 + lr][f * 32 + lg * 8]);
                oacc[c] = __builtin_amdgcn_mfma_f32_16x16x32_bf16(va, pb, oacc[c], 0, 0, 0);
            }
        }
    }

    // O^T layout: col q = lr, row d = 16c + 4lg + j -> float4 stores
    const float linv = 1.f / lrow;
    float* op = o + ((size_t)b * N + q0 + w * 16 + lr) * 1024 + h * 64;
#pragma unroll
    for (int c = 0; c < 4; ++c) {
        float4 v = { oacc[c][0] * linv, oacc[c][1] * linv,
                     oacc[c][2] * linv, oacc[c][3] * linv };
        *reinterpret_cast<float4*>(op + c * 16 + lg * 4) = v;
    }
}

// ---- fused residual + LayerNorm (fp32), optional bf16 copy -----------------
__global__ __launch_bounds__(256) void ln_res(const float* __restrict__ a,
                                              const float* __restrict__ r,
                                              const float* __restrict__ g,
                                              const float* __restrict__ be,
                                              float* __restrict__ y,
                                              bf16* __restrict__ yb) {
    const int row = blockIdx.x, t = threadIdx.x;
    float4 va = reinterpret_cast<const float4*>(a + (size_t)row * 1024)[t];
    float4 vr = reinterpret_cast<const float4*>(r + (size_t)row * 1024)[t];
    float v0 = va.x + vr.x, v1 = va.y + vr.y, v2 = va.z + vr.z, v3 = va.w + vr.w;
    float s1 = v0 + v1 + v2 + v3;
    float s2 = v0 * v0 + v1 * v1 + v2 * v2 + v3 * v3;
#pragma unroll
    for (int m = 1; m < 64; m <<= 1) {
        s1 += __shfl_xor(s1, m, 64);
        s2 += __shfl_xor(s2, m, 64);
    }
    __shared__ float ws1[4], ws2[4];
    if ((t & 63) == 0) { ws1[t >> 6] = s1; ws2[t >> 6] = s2; }
    __syncthreads();
    s1 = ws1[0] + ws1[1] + ws1[2] + ws1[3];
    s2 = ws2[0] + ws2[1] + ws2[2] + ws2[3];
    const float mean = s1 * (1.f / 1024.f);
    const float var = s2 * (1.f / 1024.f) - mean * mean;
    const float rstd = rsqrtf(var + 1e-5f);
    float4 gg = reinterpret_cast<const float4*>(g)[t];
    float4 bb = reinterpret_cast<const float4*>(be)[t];
    float o0 = (v0 - mean) * rstd * gg.x + bb.x;
    float o1 = (v1 - mean) * rstd * gg.y + bb.y;
    float o2 = (v2 - mean) * rstd * gg.z + bb.z;
    float o3 = (v3 - mean) * rstd * gg.w + bb.w;
    float4 out = { o0, o1, o2, o3 };
    reinterpret_cast<float4*>(y + (size_t)row * 1024)[t] = out;
    if (yb) {
        ushort4 ob = { f2b(o0), f2b(o1), f2b(o2), f2b(o3) };
        reinterpret_cast<ushort4*>(yb + (size_t)row * 1024)[t] = ob;
    }
}

// ---------------------------------------------------------------------------
extern "C" void kernel_launch(void* const* d_in, const int* in_sizes, int n_in,
                              void* d_out, int out_size, void* d_ws, size_t ws_size,
                              hipStream_t stream) {
    const float* x_in = (const float*)d_in[0];
    const float* Wqkv = (const float*)d_in[1];
    const float* bqkv = (const float*)d_in[2];
    const float* W1   = (const float*)d_in[3];
    const float* b1   = (const float*)d_in[4];
    const float* W2   = (const float*)d_in[5];
    const float* b2   = (const float*)d_in[6];
    const float* g1   = (const float*)d_in[7];
    const float* be1  = (const float*)d_in[8];
    const float* g2   = (const float*)d_in[9];
    const float* be2  = (const float*)d_in[10];

    const int Bv = 2, N = 2048, L = 4, Hh = 16;
    const int R = Bv * N;  // 4096 token rows

    char* p = (char*)d_ws;
    auto alloc = [&](size_t bytes) { char* r = p; p += (bytes + 255) & ~(size_t)255; return r; };
    bf16*  Wqkvt = (bf16*)alloc((size_t)L * 3072 * 1024 * 2);
    bf16*  W1t   = (bf16*)alloc((size_t)L * 4096 * 1024 * 2);
    bf16*  W2t   = (bf16*)alloc((size_t)L * 1024 * 4096 * 2);
    bf16*  xb    = (bf16*)alloc((size_t)R * 1024 * 2);
    bf16*  qkvb  = (bf16*)alloc((size_t)R * 3072 * 2);
    float* obuf  = (float*)alloc((size_t)R * 1024 * 4);
    float* hbuf  = (float*)alloc((size_t)R * 1024 * 4);
    bf16*  hb    = (bf16*)alloc((size_t)R * 1024 * 2);
    bf16*  f1b   = (bf16*)alloc((size_t)R * 4096 * 2);
    float* xcur  = (float*)alloc((size_t)R * 1024 * 4);
    float* f2buf = obuf;        // obuf dead after LN1 -> reuse for f2
    bf16*  vtg   = (bf16*)hbuf; // 8.4MB V^T; hbuf region dead during qkv-gemm/attn

    transpose_cast<<<dim3(3072 / 32, 1024 / 32, L), dim3(32, 8), 0, stream>>>(Wqkv, Wqkvt, 1024, 3072);
    transpose_cast<<<dim3(4096 / 32, 1024 / 32, L), dim3(32, 8), 0, stream>>>(W1, W1t, 1024, 4096);
    transpose_cast<<<dim3(1024 / 32, 4096 / 32, L), dim3(32, 8), 0, stream>>>(W2, W2t, 4096, 1024);
    cast_bf16_k<<<(R * 1024 / 4 + 255) / 256, 256, 0, stream>>>(x_in, xb, R * 1024 / 4);

    const float* xres = x_in;
    for (int l = 0; l < L; ++l) {
        // qkv = x @ Wqkv + bqkv  -> bf16
        gemm_bf16<0><<<(3072 / 128) * (R / 128), 256, 0, stream>>>(
            xb, Wqkvt + (size_t)l * 3072 * 1024, bqkv + l * 3072, qkvb, R, 3072, 1024, 3072 / 128);
        // V^T per (b,h): [dh][N]
        vtrans<<<dim3(N / 32, 2, Bv * Hh), dim3(32, 8), 0, stream>>>(qkvb, vtg, N);
        // o = softmax(q k^T / 32) v
        attn_fwd<<<(N / 64) * (Bv * Hh), 256, 0, stream>>>(qkvb, vtg, obuf, N);
        // h = LN(o + x)   (overwrites vtg region -- attn already done)
        ln_res<<<R, 256, 0, stream>>>(obuf, xres, g1 + l * 1024, be1 + l * 1024, hbuf, hb);
        // f1 = gelu(h @ W1 + b1) -> bf16
        gemm_bf16<1><<<(4096 / 128) * (R / 128), 256, 0, stream>>>(
            hb, W1t + (size_t)l * 4096 * 1024, b1 + l * 4096, f1b, R, 4096, 1024, 4096 / 128);
        // f2 = gelu(f1 @ W2 + b2) -> fp32
        gemm_bf16<2><<<(1024 / 128) * (R / 128), 256, 0, stream>>>(
            f1b, W2t + (size_t)l * 1024 * 4096, b2 + l * 1024, f2buf, R, 1024, 4096, 1024 / 128);
        // x = LN(f2 + h), also emit bf16 copy for next layer's GEMM
        float* xn = (l == L - 1) ? (float*)d_out : xcur;
        ln_res<<<R, 256, 0, stream>>>(f2buf, hbuf, g2 + l * 1024, be2 + l * 1024, xn, xb);
        xres = xn;
    }
}